// Round 22
// baseline (164.087 us; speedup 1.0000x reference)
//
#include <hip/hip_runtime.h>

#define N_NODES 50000
#define N_EDGES 800000
#define F_IN 128
#define F_HID 256
#define F_OUT 64

#define SCAN_NB ((N_NODES + 255) / 256)  // 196

// ---------------- workspace layout (bytes) ----------------
#define OFF_ROWPTR 0ull
#define OFF_CNT    (256ull << 10)
#define OFF_DINV   (768ull << 10)
#define OFF_BSUM   (984ull << 10)
#define OFF_EIDX   (1ull << 20)                      // ushort[E] = 1.6 MB
#define OFF_ELOC   ((2ull << 20) + (640ull << 10))   // ushort[E] = 1.6 MB
#define OFF_XB     ((4ull << 20) + (256ull << 10))
#define OFF_T2B    ((17ull << 20) + (512ull << 10))
#define OFF_W1F    (25ull << 20)                     // 64 KB (4096 uint4)
#define OFF_W2F    ((25ull << 20) + (128ull << 10))  // 32 KB (2048 uint4)

// ---------------- types / helpers ----------------

typedef __attribute__((ext_vector_type(8))) short bfrag;   // 8 bf16 (4 VGPR)
typedef __attribute__((ext_vector_type(4))) float f4acc;   // 4 f32 acc

__device__ __forceinline__ unsigned f2bf(float f) {  // RNE to bf16 (low 16 bits)
    unsigned u = __float_as_uint(f);
    return (u + 0x7FFFu + ((u >> 16) & 1u)) >> 16;
}
__device__ __forceinline__ float bflo(unsigned u) { return __uint_as_float(u << 16); }
__device__ __forceinline__ float bfhi(unsigned u) { return __uint_as_float(u & 0xFFFF0000u); }
__device__ __forceinline__ bfrag as_bfrag(uint4 v) {
    union { uint4 u; bfrag b; } x; x.u = v; return x.b;
}

// ---------------- weight prep (fragment-pack W1/W2) + cnt zeroing, one dispatch ----------------
__global__ __launch_bounds__(256) void wprep_zero_kernel(const float* __restrict__ W1,
                                                         const float* __restrict__ W2,
                                                         unsigned* __restrict__ W1f,
                                                         unsigned* __restrict__ W2f,
                                                         int* __restrict__ cnt) {
    int i = blockIdx.x * 256 + threadIdx.x;
    if (i < 16384) {
        int jj = i & 3, l = (i >> 2) & 63, nt = (i >> 8) & 15, ks = i >> 12;
        int k = ks * 32 + ((l >> 4) & 3) * 8 + 2 * jj;
        int n = nt * 16 + (l & 15);
        W1f[i] = f2bf(W1[(size_t)k * F_HID + n]) | (f2bf(W1[(size_t)(k + 1) * F_HID + n]) << 16);
    } else if (i < 24576) {
        int i2 = i - 16384;
        int jj = i2 & 3, l = (i2 >> 2) & 63, nt = (i2 >> 8) & 3, ks = i2 >> 10;
        int k = ks * 32 + ((l >> 4) & 3) * 8 + 2 * jj;
        int n = nt * 16 + (l & 15);
        W2f[i2] = f2bf(W2[(size_t)k * F_OUT + n]) | (f2bf(W2[(size_t)(k + 1) * F_OUT + n]) << 16);
    }
    if (i < N_NODES) cnt[i] = 0;
}

// ---------------- CSR build ----------------

// hist + per-edge local offset (atomic return), coalesced ushort write
__global__ void hist_elocal_kernel(const int* __restrict__ cols, int* __restrict__ cnt,
                                   unsigned short* __restrict__ elocal, int e) {
    int i = blockIdx.x * blockDim.x + threadIdx.x;
    if (i < e) {
        int old = atomicAdd(&cnt[cols[i]], 1);
        elocal[i] = (unsigned short)old;
    }
}

__global__ __launch_bounds__(256) void bsum_kernel(const int* __restrict__ cnt, int* __restrict__ bsum) {
    __shared__ int s[256];
    int t = threadIdx.x;
    int i = blockIdx.x * 256 + t;
    int v = (i < N_NODES) ? cnt[i] : 0;
    s[t] = v;
    __syncthreads();
#pragma unroll
    for (int off = 128; off > 0; off >>= 1) {
        if (t < off) s[t] += s[t + off];
        __syncthreads();
    }
    if (t == 0) bsum[blockIdx.x] = s[0];
}

__global__ __launch_bounds__(256) void bscan_kernel(int* __restrict__ bsum) {
    __shared__ int s[256];
    int t = threadIdx.x;
    int v = (t < SCAN_NB) ? bsum[t] : 0;
    s[t] = v;
    __syncthreads();
#pragma unroll
    for (int off = 1; off < 256; off <<= 1) {
        int u = (t >= off) ? s[t - off] : 0;
        __syncthreads();
        s[t] += u;
        __syncthreads();
    }
    if (t < SCAN_NB) bsum[t] = s[t] - v;  // exclusive
}

__global__ __launch_bounds__(256) void rowptr_kernel(const int* __restrict__ cnt,
                                                     const int* __restrict__ bsum,
                                                     int* __restrict__ row_ptr,
                                                     float* __restrict__ dinv) {
    __shared__ int s[256];
    int t = threadIdx.x;
    int i = blockIdx.x * 256 + t;
    int v = (i < N_NODES) ? cnt[i] : 0;
    s[t] = v;
    __syncthreads();
#pragma unroll
    for (int off = 1; off < 256; off <<= 1) {
        int u = (t >= off) ? s[t - off] : 0;
        __syncthreads();
        s[t] += u;
        __syncthreads();
    }
    int excl = s[t] - v + bsum[blockIdx.x];
    if (i < N_NODES) {
        row_ptr[i] = excl;
        dinv[i] = rsqrtf((float)v + 1.0f);  // +1 self loop
    }
    if (blockIdx.x == 0 && t == 0) row_ptr[N_NODES] = N_EDGES;
}

// atomic-free scatter (pos = row_ptr[c] + elocal[i]) + cvt x -> pre-scaled bf16
__global__ void scatter_cvt_kernel(const int* __restrict__ rows, const int* __restrict__ cols,
                                   const int* __restrict__ row_ptr,
                                   const unsigned short* __restrict__ elocal,
                                   unsigned short* __restrict__ eidx,
                                   const float* __restrict__ x, const float* __restrict__ dinv,
                                   unsigned* __restrict__ xb) {
    int i = blockIdx.x * blockDim.x + threadIdx.x;
    if (i < N_EDGES) {
        int c = cols[i];
        int pos = row_ptr[c] + (int)elocal[i];
        eidx[pos] = (unsigned short)rows[i];  // fire-and-forget scattered store
    }
    if (i < N_NODES * (F_IN / 8)) {  // 800000 exactly
        int node = i >> 4;
        float d = dinv[node];
        float4 a = ((const float4*)x)[(size_t)i * 2];
        float4 b = ((const float4*)x)[(size_t)i * 2 + 1];
        uint4 o;
        o.x = f2bf(d * a.x) | (f2bf(d * a.y) << 16);
        o.y = f2bf(d * a.z) | (f2bf(d * a.w) << 16);
        o.z = f2bf(d * b.x) | (f2bf(d * b.y) << 16);
        o.w = f2bf(d * b.z) | (f2bf(d * b.w) << 16);
        ((uint4*)xb)[i] = o;
    }
}

// ---------------- fused: bf16-gather -> MFMA @W1+b1+relu -> MFMA @W2 -> t2b ----
// Phase A: TWO nodes per lane-group interleaved in ONE loop -> 16 loads in flight
// (was 2 serial passes of 8). LDS 16896 B aliased: AxP[32][68] u32 / HcS[32][264] ushort.
// MFMA v_mfma_f32_16x16x32_bf16; C/D: col=lane&15, row=(lane>>4)*4+reg (m89).
// __launch_bounds__(256,4): DO NOT raise (r14/r15: VGPR cap -> scratch spill).
__global__ __launch_bounds__(256, 4) void fused12_kernel(const unsigned* __restrict__ xb,
                                                         const int* __restrict__ row_ptr,
                                                         const unsigned short* __restrict__ eidx,
                                                         const float* __restrict__ dinv,
                                                         const uint4* __restrict__ W1f,
                                                         const float* __restrict__ b1,
                                                         const uint4* __restrict__ W2f,
                                                         unsigned short* __restrict__ t2b) {
    __shared__ __align__(16) char smem_raw[16896];
    unsigned* AxP = (unsigned*)smem_raw;              // [32][68] packed bf16 pairs
    unsigned short* HcS = (unsigned short*)smem_raw;  // [32][264] bf16 H (aliases AxP)

    int tid = threadIdx.x;
    int bm0 = blockIdx.x * 32;
    const uint4* xb4 = (const uint4*)xb;

    // ---- phase A: dual-node interleaved gather (16 loads in flight/lane) ----
    {
        int f8 = tid & 15;
        int ng = tid >> 4;            // 0..15
        int c0 = bm0 + ng;            // always < N_NODES (bm0 <= 49984)
        int c1 = bm0 + 16 + ng;       // may be >= N_NODES in last block
        bool v1 = (c1 < N_NODES);

        float a0[8], a1[8];
        {   // self rows (pre-scaled)
            uint4 S0 = xb4[(size_t)c0 * 16 + f8];
            a0[0] = bflo(S0.x); a0[1] = bfhi(S0.x);
            a0[2] = bflo(S0.y); a0[3] = bfhi(S0.y);
            a0[4] = bflo(S0.z); a0[5] = bfhi(S0.z);
            a0[6] = bflo(S0.w); a0[7] = bfhi(S0.w);
        }
        if (v1) {
            uint4 S1 = xb4[(size_t)c1 * 16 + f8];
            a1[0] = bflo(S1.x); a1[1] = bfhi(S1.x);
            a1[2] = bflo(S1.y); a1[3] = bfhi(S1.y);
            a1[4] = bflo(S1.z); a1[5] = bfhi(S1.z);
            a1[6] = bflo(S1.w); a1[7] = bfhi(S1.w);
        } else {
#pragma unroll
            for (int q = 0; q < 8; ++q) a1[q] = 0.f;
        }

        int k0 = row_ptr[c0], k0e = row_ptr[c0 + 1];
        int k1 = 0, k1e = 0;
        if (v1) { k1 = row_ptr[c1]; k1e = row_ptr[c1 + 1]; }
        int k0m = k0 + ((k0e - k0) & ~7);
        int k1m = k1 + ((k1e - k1) & ~7);

        while (k0 < k0m || k1 < k1m) {
            uint4 U0[8], U1[8];
            bool d0 = k0 < k0m, d1 = k1 < k1m;
            if (d0) {
                int r[8];
#pragma unroll
                for (int j = 0; j < 8; ++j) r[j] = eidx[k0 + j];
#pragma unroll
                for (int j = 0; j < 8; ++j) U0[j] = xb4[(size_t)r[j] * 16 + f8];
            }
            if (d1) {
                int r[8];
#pragma unroll
                for (int j = 0; j < 8; ++j) r[j] = eidx[k1 + j];
#pragma unroll
                for (int j = 0; j < 8; ++j) U1[j] = xb4[(size_t)r[j] * 16 + f8];
            }
            if (d0) {
#pragma unroll
                for (int j = 0; j < 8; ++j) {
                    a0[0] += bflo(U0[j].x); a0[1] += bfhi(U0[j].x);
                    a0[2] += bflo(U0[j].y); a0[3] += bfhi(U0[j].y);
                    a0[4] += bflo(U0[j].z); a0[5] += bfhi(U0[j].z);
                    a0[6] += bflo(U0[j].w); a0[7] += bfhi(U0[j].w);
                }
                k0 += 8;
            }
            if (d1) {
#pragma unroll
                for (int j = 0; j < 8; ++j) {
                    a1[0] += bflo(U1[j].x); a1[1] += bfhi(U1[j].x);
                    a1[2] += bflo(U1[j].y); a1[3] += bfhi(U1[j].y);
                    a1[4] += bflo(U1[j].z); a1[5] += bfhi(U1[j].z);
                    a1[6] += bflo(U1[j].w); a1[7] += bfhi(U1[j].w);
                }
                k1 += 8;
            }
        }
        // masked tails (<=7 edges each)
        if (k0 < k0e) {
            int r[8];
            float m[8];
#pragma unroll
            for (int j = 0; j < 8; ++j) {
                int idx = (k0 + j < k0e) ? k0 + j : k0e - 1;
                r[j] = eidx[idx];
                m[j] = (k0 + j < k0e) ? 1.f : 0.f;
            }
            uint4 U[8];
#pragma unroll
            for (int j = 0; j < 8; ++j) U[j] = xb4[(size_t)r[j] * 16 + f8];
#pragma unroll
            for (int j = 0; j < 8; ++j) {
                a0[0] = fmaf(m[j], bflo(U[j].x), a0[0]);
                a0[1] = fmaf(m[j], bfhi(U[j].x), a0[1]);
                a0[2] = fmaf(m[j], bflo(U[j].y), a0[2]);
                a0[3] = fmaf(m[j], bfhi(U[j].y), a0[3]);
                a0[4] = fmaf(m[j], bflo(U[j].z), a0[4]);
                a0[5] = fmaf(m[j], bfhi(U[j].z), a0[5]);
                a0[6] = fmaf(m[j], bflo(U[j].w), a0[6]);
                a0[7] = fmaf(m[j], bfhi(U[j].w), a0[7]);
            }
        }
        if (v1 && k1 < k1e) {
            int r[8];
            float m[8];
#pragma unroll
            for (int j = 0; j < 8; ++j) {
                int idx = (k1 + j < k1e) ? k1 + j : k1e - 1;
                r[j] = eidx[idx];
                m[j] = (k1 + j < k1e) ? 1.f : 0.f;
            }
            uint4 U[8];
#pragma unroll
            for (int j = 0; j < 8; ++j) U[j] = xb4[(size_t)r[j] * 16 + f8];
#pragma unroll
            for (int j = 0; j < 8; ++j) {
                a1[0] = fmaf(m[j], bflo(U[j].x), a1[0]);
                a1[1] = fmaf(m[j], bfhi(U[j].x), a1[1]);
                a1[2] = fmaf(m[j], bflo(U[j].y), a1[2]);
                a1[3] = fmaf(m[j], bfhi(U[j].y), a1[3]);
                a1[4] = fmaf(m[j], bflo(U[j].z), a1[4]);
                a1[5] = fmaf(m[j], bfhi(U[j].z), a1[5]);
                a1[6] = fmaf(m[j], bflo(U[j].w), a1[6]);
                a1[7] = fmaf(m[j], bfhi(U[j].w), a1[7]);
            }
        }
        {
            float dc0 = dinv[c0];
#pragma unroll
            for (int q = 0; q < 8; ++q) a0[q] *= dc0;
            uint4 P;
            P.x = f2bf(a0[0]) | (f2bf(a0[1]) << 16);
            P.y = f2bf(a0[2]) | (f2bf(a0[3]) << 16);
            P.z = f2bf(a0[4]) | (f2bf(a0[5]) << 16);
            P.w = f2bf(a0[6]) | (f2bf(a0[7]) << 16);
            *(uint4*)&AxP[ng * 68 + f8 * 4] = P;
        }
        {
            float dc1 = v1 ? dinv[c1] : 0.f;
#pragma unroll
            for (int q = 0; q < 8; ++q) a1[q] *= dc1;
            uint4 P;
            P.x = f2bf(a1[0]) | (f2bf(a1[1]) << 16);
            P.y = f2bf(a1[2]) | (f2bf(a1[3]) << 16);
            P.z = f2bf(a1[4]) | (f2bf(a1[5]) << 16);
            P.w = f2bf(a1[6]) | (f2bf(a1[7]) << 16);
            *(uint4*)&AxP[(16 + ng) * 68 + f8 * 4] = P;
        }
    }
    __syncthreads();

    // ---- wave geometry ----
    int w = tid >> 6;
    int l = tid & 63;
    int mtile = w >> 1;
    int nhalf = w & 1;
    int lr = l & 15;
    int lq = l >> 4;

    // ---- phase B: H[32x256] = Ax @ W1 via MFMA; 32 mfma/wave ----
    f4acc acc1[8] = {};
#pragma unroll
    for (int ks = 0; ks < 4; ++ks) {
        bfrag a = as_bfrag(*(const uint4*)&AxP[(mtile * 16 + lr) * 68 + ks * 16 + lq * 4]);
#pragma unroll
        for (int nt = 0; nt < 8; ++nt) {
            bfrag b = as_bfrag(W1f[(ks * 16 + nhalf * 8 + nt) * 64 + l]);
            acc1[nt] = __builtin_amdgcn_mfma_f32_16x16x32_bf16(a, b, acc1[nt], 0, 0, 0);
        }
    }
    __syncthreads();  // all AxP reads done before HcS overwrite

    // ---- H epilogue: +b1, relu, bf16, to LDS ----
#pragma unroll
    for (int nt = 0; nt < 8; ++nt) {
        int col = nhalf * 128 + nt * 16 + lr;
        float bias = b1[col];
#pragma unroll
        for (int r = 0; r < 4; ++r) {
            int row = mtile * 16 + lq * 4 + r;
            float v = fmaxf(acc1[nt][r] + bias, 0.f);
            HcS[row * 264 + col] = (unsigned short)f2bf(v);
        }
    }
    __syncthreads();

    // ---- phase C: t2 = H @ W2 via MFMA; 16 mfma/wave ----
    f4acc acc2[2] = {};
#pragma unroll
    for (int ks = 0; ks < 8; ++ks) {
        bfrag a = as_bfrag(*(const uint4*)&HcS[(mtile * 16 + lr) * 264 + ks * 32 + lq * 8]);
#pragma unroll
        for (int nt = 0; nt < 2; ++nt) {
            bfrag b = as_bfrag(W2f[(ks * 4 + nhalf * 2 + nt) * 64 + l]);
            acc2[nt] = __builtin_amdgcn_mfma_f32_16x16x32_bf16(a, b, acc2[nt], 0, 0, 0);
        }
    }

    // ---- write t2b = bf16(dinv * acc2) ----
#pragma unroll
    for (int nt = 0; nt < 2; ++nt) {
        int col = nhalf * 32 + nt * 16 + lr;
#pragma unroll
        for (int r = 0; r < 4; ++r) {
            int row = bm0 + mtile * 16 + lq * 4 + r;
            if (row < N_NODES) {
                float d = dinv[row];
                t2b[(size_t)row * 64 + col] = (unsigned short)f2bf(d * acc2[nt][r]);
            }
        }
    }
}

// ---------------- layer 2 pull-gather: unmasked unroll-16 main + masked-8 tail ----
__global__ __launch_bounds__(256) void l2_gather_kernel(const unsigned* __restrict__ t2b,
                                                        const int* __restrict__ row_ptr,
                                                        const unsigned short* __restrict__ eidx,
                                                        const float* __restrict__ dinv,
                                                        const float* __restrict__ b2,
                                                        float* __restrict__ out) {
    int tid = threadIdx.x;
    int f8 = tid & 7;
    int nl = tid >> 3;
    int c = blockIdx.x * 32 + nl;
    if (c >= N_NODES) return;
    uint4 S = ((const uint4*)t2b)[(size_t)c * 8 + f8];
    float acc[8];
    acc[0] = bflo(S.x); acc[1] = bfhi(S.x);
    acc[2] = bflo(S.y); acc[3] = bfhi(S.y);
    acc[4] = bflo(S.z); acc[5] = bfhi(S.z);
    acc[6] = bflo(S.w); acc[7] = bfhi(S.w);
    int k = row_ptr[c];
    int k1 = row_ptr[c + 1];
    int kmain = k + ((k1 - k) & ~15);
    for (; k < kmain; k += 16) {
        int r[16];
#pragma unroll
        for (int j = 0; j < 16; ++j) r[j] = eidx[k + j];
        uint4 U[16];
#pragma unroll
        for (int j = 0; j < 16; ++j) U[j] = ((const uint4*)t2b)[(size_t)r[j] * 8 + f8];
#pragma unroll
        for (int j = 0; j < 16; ++j) {
            acc[0] += bflo(U[j].x); acc[1] += bfhi(U[j].x);
            acc[2] += bflo(U[j].y); acc[3] += bfhi(U[j].y);
            acc[4] += bflo(U[j].z); acc[5] += bfhi(U[j].z);
            acc[6] += bflo(U[j].w); acc[7] += bfhi(U[j].w);
        }
    }
    for (; k < k1; k += 8) {
        int r[8];
        float m[8];
#pragma unroll
        for (int j = 0; j < 8; ++j) {
            int idx = (k + j < k1) ? k + j : k1 - 1;
            r[j] = eidx[idx];
            m[j] = (k + j < k1) ? 1.f : 0.f;
        }
        uint4 U[8];
#pragma unroll
        for (int j = 0; j < 8; ++j) U[j] = ((const uint4*)t2b)[(size_t)r[j] * 8 + f8];
#pragma unroll
        for (int j = 0; j < 8; ++j) {
            acc[0] = fmaf(m[j], bflo(U[j].x), acc[0]);
            acc[1] = fmaf(m[j], bfhi(U[j].x), acc[1]);
            acc[2] = fmaf(m[j], bflo(U[j].y), acc[2]);
            acc[3] = fmaf(m[j], bfhi(U[j].y), acc[3]);
            acc[4] = fmaf(m[j], bflo(U[j].z), acc[4]);
            acc[5] = fmaf(m[j], bfhi(U[j].z), acc[5]);
            acc[6] = fmaf(m[j], bflo(U[j].w), acc[6]);
            acc[7] = fmaf(m[j], bfhi(U[j].w), acc[7]);
        }
    }
    float dc = dinv[c];
    float4 b2a = *(const float4*)&b2[f8 * 8];
    float4 b2b = *(const float4*)&b2[f8 * 8 + 4];
    float4 o0, o1;
    o0.x = fmaf(dc, acc[0], b2a.x);
    o0.y = fmaf(dc, acc[1], b2a.y);
    o0.z = fmaf(dc, acc[2], b2a.z);
    o0.w = fmaf(dc, acc[3], b2a.w);
    o1.x = fmaf(dc, acc[4], b2b.x);
    o1.y = fmaf(dc, acc[5], b2b.y);
    o1.z = fmaf(dc, acc[6], b2b.z);
    o1.w = fmaf(dc, acc[7], b2b.w);
    ((float4*)out)[(size_t)c * 16 + f8 * 2] = o0;
    ((float4*)out)[(size_t)c * 16 + f8 * 2 + 1] = o1;
}

// ---------------- launch ----------------

extern "C" void kernel_launch(void* const* d_in, const int* in_sizes, int n_in,
                              void* d_out, int out_size, void* d_ws, size_t ws_size,
                              hipStream_t stream) {
    const float* x = (const float*)d_in[0];
    const int* edge_index = (const int*)d_in[1];
    const float* W1 = (const float*)d_in[2];
    const float* b1 = (const float*)d_in[3];
    const float* W2 = (const float*)d_in[4];
    const float* b2 = (const float*)d_in[5];
    float* out = (float*)d_out;

    const int* rows = edge_index;            // source nodes
    const int* cols = edge_index + N_EDGES;  // target nodes

    char* ws = (char*)d_ws;
    int* row_ptr = (int*)(ws + OFF_ROWPTR);
    int* cnt = (int*)(ws + OFF_CNT);
    float* dinv = (float*)(ws + OFF_DINV);
    int* bsum = (int*)(ws + OFF_BSUM);
    unsigned short* eidx = (unsigned short*)(ws + OFF_EIDX);
    unsigned short* elocal = (unsigned short*)(ws + OFF_ELOC);
    unsigned* xb = (unsigned*)(ws + OFF_XB);
    unsigned* t2b = (unsigned*)(ws + OFF_T2B);
    unsigned* W1f = (unsigned*)(ws + OFF_W1F);
    unsigned* W2f = (unsigned*)(ws + OFF_W2F);

    const int BT = 256;

    wprep_zero_kernel<<<SCAN_NB, 256, 0, stream>>>(W1, W2, W1f, W2f, cnt);
    hist_elocal_kernel<<<(N_EDGES + BT - 1) / BT, BT, 0, stream>>>(cols, cnt, elocal, N_EDGES);
    bsum_kernel<<<SCAN_NB, 256, 0, stream>>>(cnt, bsum);
    bscan_kernel<<<1, 256, 0, stream>>>(bsum);
    rowptr_kernel<<<SCAN_NB, 256, 0, stream>>>(cnt, bsum, row_ptr, dinv);
    scatter_cvt_kernel<<<(N_EDGES + BT - 1) / BT, BT, 0, stream>>>(
        rows, cols, row_ptr, elocal, eidx, x, dinv, xb);

    fused12_kernel<<<(N_NODES + 31) / 32, 256, 0, stream>>>(
        xb, row_ptr, eidx, dinv, (const uint4*)W1f, b1, (const uint4*)W2f, (unsigned short*)t2b);
    l2_gather_kernel<<<(N_NODES + 31) / 32, 256, 0, stream>>>(t2b, row_ptr, eidx, dinv, b2, out);
}

// Round 23
// 122.930 us; speedup vs baseline: 1.3348x; 1.3348x over previous
//
#include <hip/hip_runtime.h>

#define N_NODES 50000
#define N_EDGES 800000
#define F_IN 128
#define F_HID 256
#define F_OUT 64

#define SCAN_NB ((N_NODES + 255) / 256)  // 196

// ---------------- workspace layout (bytes) ----------------
#define OFF_ROWPTR 0ull
#define OFF_CNT    (256ull << 10)
#define OFF_DINV   (768ull << 10)
#define OFF_BSUM   (984ull << 10)
#define OFF_EIDX   (1ull << 20)                      // ushort[E] = 1.6 MB
#define OFF_ELOC   ((2ull << 20) + (640ull << 10))   // ushort[E] = 1.6 MB
#define OFF_XB     ((4ull << 20) + (256ull << 10))
#define OFF_T2B    ((17ull << 20) + (512ull << 10))
#define OFF_W1F    (25ull << 20)                     // 64 KB (4096 uint4)
#define OFF_W2F    ((25ull << 20) + (128ull << 10))  // 32 KB (2048 uint4)

// ---------------- types / helpers ----------------

typedef __attribute__((ext_vector_type(8))) short bfrag;   // 8 bf16 (4 VGPR)
typedef __attribute__((ext_vector_type(4))) float f4acc;   // 4 f32 acc

__device__ __forceinline__ unsigned f2bf(float f) {  // RNE to bf16 (low 16 bits)
    unsigned u = __float_as_uint(f);
    return (u + 0x7FFFu + ((u >> 16) & 1u)) >> 16;
}
__device__ __forceinline__ float bflo(unsigned u) { return __uint_as_float(u << 16); }
__device__ __forceinline__ float bfhi(unsigned u) { return __uint_as_float(u & 0xFFFF0000u); }
__device__ __forceinline__ bfrag as_bfrag(uint4 v) {
    union { uint4 u; bfrag b; } x; x.u = v; return x.b;
}

// ---------------- weight prep (fragment-pack W1/W2) + cnt zeroing, one dispatch ----------------
__global__ __launch_bounds__(256) void wprep_zero_kernel(const float* __restrict__ W1,
                                                         const float* __restrict__ W2,
                                                         unsigned* __restrict__ W1f,
                                                         unsigned* __restrict__ W2f,
                                                         int* __restrict__ cnt) {
    int i = blockIdx.x * 256 + threadIdx.x;
    if (i < 16384) {
        int jj = i & 3, l = (i >> 2) & 63, nt = (i >> 8) & 15, ks = i >> 12;
        int k = ks * 32 + ((l >> 4) & 3) * 8 + 2 * jj;
        int n = nt * 16 + (l & 15);
        W1f[i] = f2bf(W1[(size_t)k * F_HID + n]) | (f2bf(W1[(size_t)(k + 1) * F_HID + n]) << 16);
    } else if (i < 24576) {
        int i2 = i - 16384;
        int jj = i2 & 3, l = (i2 >> 2) & 63, nt = (i2 >> 8) & 3, ks = i2 >> 10;
        int k = ks * 32 + ((l >> 4) & 3) * 8 + 2 * jj;
        int n = nt * 16 + (l & 15);
        W2f[i2] = f2bf(W2[(size_t)k * F_OUT + n]) | (f2bf(W2[(size_t)(k + 1) * F_OUT + n]) << 16);
    }
    if (i < N_NODES) cnt[i] = 0;
}

// ---------------- CSR build ----------------

// hist + per-edge local offset (atomic return), coalesced ushort write
__global__ void hist_elocal_kernel(const int* __restrict__ cols, int* __restrict__ cnt,
                                   unsigned short* __restrict__ elocal, int e) {
    int i = blockIdx.x * blockDim.x + threadIdx.x;
    if (i < e) {
        int old = atomicAdd(&cnt[cols[i]], 1);
        elocal[i] = (unsigned short)old;
    }
}

__global__ __launch_bounds__(256) void bsum_kernel(const int* __restrict__ cnt, int* __restrict__ bsum) {
    __shared__ int s[256];
    int t = threadIdx.x;
    int i = blockIdx.x * 256 + t;
    int v = (i < N_NODES) ? cnt[i] : 0;
    s[t] = v;
    __syncthreads();
#pragma unroll
    for (int off = 128; off > 0; off >>= 1) {
        if (t < off) s[t] += s[t + off];
        __syncthreads();
    }
    if (t == 0) bsum[blockIdx.x] = s[0];
}

__global__ __launch_bounds__(256) void bscan_kernel(int* __restrict__ bsum) {
    __shared__ int s[256];
    int t = threadIdx.x;
    int v = (t < SCAN_NB) ? bsum[t] : 0;
    s[t] = v;
    __syncthreads();
#pragma unroll
    for (int off = 1; off < 256; off <<= 1) {
        int u = (t >= off) ? s[t - off] : 0;
        __syncthreads();
        s[t] += u;
        __syncthreads();
    }
    if (t < SCAN_NB) bsum[t] = s[t] - v;  // exclusive
}

__global__ __launch_bounds__(256) void rowptr_kernel(const int* __restrict__ cnt,
                                                     const int* __restrict__ bsum,
                                                     int* __restrict__ row_ptr,
                                                     float* __restrict__ dinv) {
    __shared__ int s[256];
    int t = threadIdx.x;
    int i = blockIdx.x * 256 + t;
    int v = (i < N_NODES) ? cnt[i] : 0;
    s[t] = v;
    __syncthreads();
#pragma unroll
    for (int off = 1; off < 256; off <<= 1) {
        int u = (t >= off) ? s[t - off] : 0;
        __syncthreads();
        s[t] += u;
        __syncthreads();
    }
    int excl = s[t] - v + bsum[blockIdx.x];
    if (i < N_NODES) {
        row_ptr[i] = excl;
        dinv[i] = rsqrtf((float)v + 1.0f);  // +1 self loop
    }
    if (blockIdx.x == 0 && t == 0) row_ptr[N_NODES] = N_EDGES;
}

// atomic-free scatter (pos = row_ptr[c] + elocal[i]) + cvt x -> pre-scaled bf16
__global__ void scatter_cvt_kernel(const int* __restrict__ rows, const int* __restrict__ cols,
                                   const int* __restrict__ row_ptr,
                                   const unsigned short* __restrict__ elocal,
                                   unsigned short* __restrict__ eidx,
                                   const float* __restrict__ x, const float* __restrict__ dinv,
                                   unsigned* __restrict__ xb) {
    int i = blockIdx.x * blockDim.x + threadIdx.x;
    if (i < N_EDGES) {
        int c = cols[i];
        int pos = row_ptr[c] + (int)elocal[i];
        eidx[pos] = (unsigned short)rows[i];  // fire-and-forget scattered store
    }
    if (i < N_NODES * (F_IN / 8)) {  // 800000 exactly
        int node = i >> 4;
        float d = dinv[node];
        float4 a = ((const float4*)x)[(size_t)i * 2];
        float4 b = ((const float4*)x)[(size_t)i * 2 + 1];
        uint4 o;
        o.x = f2bf(d * a.x) | (f2bf(d * a.y) << 16);
        o.y = f2bf(d * a.z) | (f2bf(d * a.w) << 16);
        o.z = f2bf(d * b.x) | (f2bf(d * b.y) << 16);
        o.w = f2bf(d * b.z) | (f2bf(d * b.w) << 16);
        ((uint4*)xb)[i] = o;
    }
}

// ---------------- fused: bf16-gather -> MFMA @W1+b1+relu -> MFMA @W2 -> t2b ----
// Phase A: r19-proven form — two serial node passes, unmasked unroll-8 + masked tail
// (8 loads in flight; VGPR 44, NO spill). r22 lesson: dual-node interleave (16 in
// flight) spills (WRITE 6->132 MB) and is 2x SLOWER. Keep <=8 uint4 live.
// LDS 16896 B aliased: AxP[32][68] u32 / HcS[32][264] ushort.
// MFMA v_mfma_f32_16x16x32_bf16; C/D: col=lane&15, row=(lane>>4)*4+reg (m89).
// __launch_bounds__(256,4): DO NOT raise (r14/r15: VGPR cap -> scratch spill).
__global__ __launch_bounds__(256, 4) void fused12_kernel(const unsigned* __restrict__ xb,
                                                         const int* __restrict__ row_ptr,
                                                         const unsigned short* __restrict__ eidx,
                                                         const float* __restrict__ dinv,
                                                         const uint4* __restrict__ W1f,
                                                         const float* __restrict__ b1,
                                                         const uint4* __restrict__ W2f,
                                                         unsigned short* __restrict__ t2b) {
    __shared__ __align__(16) char smem_raw[16896];
    unsigned* AxP = (unsigned*)smem_raw;              // [32][68] packed bf16 pairs
    unsigned short* HcS = (unsigned short*)smem_raw;  // [32][264] bf16 H (aliases AxP)

    int tid = threadIdx.x;
    int bm0 = blockIdx.x * 32;
    const uint4* xb4 = (const uint4*)xb;

    // ---- phase A: gather. Two serial passes; unmasked unroll-8 main + masked tail ----
    {
        int f8 = tid & 15;
        int ng = tid >> 4;
        for (int p = 0; p < 2; ++p) {
            int nl = p * 16 + ng;
            int c = bm0 + nl;
            float acc[8] = {};
            if (c < N_NODES) {
                uint4 S = xb4[(size_t)c * 16 + f8];  // self (pre-scaled)
                acc[0] = bflo(S.x); acc[1] = bfhi(S.x);
                acc[2] = bflo(S.y); acc[3] = bfhi(S.y);
                acc[4] = bflo(S.z); acc[5] = bfhi(S.z);
                acc[6] = bflo(S.w); acc[7] = bfhi(S.w);
                int k = row_ptr[c];
                int k1 = row_ptr[c + 1];
                int kmain = k + ((k1 - k) & ~7);
                for (; k < kmain; k += 8) {
                    int r[8];
#pragma unroll
                    for (int j = 0; j < 8; ++j) r[j] = eidx[k + j];
                    uint4 U[8];
#pragma unroll
                    for (int j = 0; j < 8; ++j) U[j] = xb4[(size_t)r[j] * 16 + f8];
#pragma unroll
                    for (int j = 0; j < 8; ++j) {
                        acc[0] += bflo(U[j].x); acc[1] += bfhi(U[j].x);
                        acc[2] += bflo(U[j].y); acc[3] += bfhi(U[j].y);
                        acc[4] += bflo(U[j].z); acc[5] += bfhi(U[j].z);
                        acc[6] += bflo(U[j].w); acc[7] += bfhi(U[j].w);
                    }
                }
                if (k < k1) {
                    int r[8];
                    float m[8];
#pragma unroll
                    for (int j = 0; j < 8; ++j) {
                        int idx = (k + j < k1) ? k + j : k1 - 1;
                        r[j] = eidx[idx];
                        m[j] = (k + j < k1) ? 1.f : 0.f;
                    }
                    uint4 U[8];
#pragma unroll
                    for (int j = 0; j < 8; ++j) U[j] = xb4[(size_t)r[j] * 16 + f8];
#pragma unroll
                    for (int j = 0; j < 8; ++j) {
                        acc[0] = fmaf(m[j], bflo(U[j].x), acc[0]);
                        acc[1] = fmaf(m[j], bfhi(U[j].x), acc[1]);
                        acc[2] = fmaf(m[j], bflo(U[j].y), acc[2]);
                        acc[3] = fmaf(m[j], bfhi(U[j].y), acc[3]);
                        acc[4] = fmaf(m[j], bflo(U[j].z), acc[4]);
                        acc[5] = fmaf(m[j], bfhi(U[j].z), acc[5]);
                        acc[6] = fmaf(m[j], bflo(U[j].w), acc[6]);
                        acc[7] = fmaf(m[j], bfhi(U[j].w), acc[7]);
                    }
                }
                float dc = dinv[c];
#pragma unroll
                for (int q = 0; q < 8; ++q) acc[q] *= dc;
            }
            uint4 P;
            P.x = f2bf(acc[0]) | (f2bf(acc[1]) << 16);
            P.y = f2bf(acc[2]) | (f2bf(acc[3]) << 16);
            P.z = f2bf(acc[4]) | (f2bf(acc[5]) << 16);
            P.w = f2bf(acc[6]) | (f2bf(acc[7]) << 16);
            *(uint4*)&AxP[nl * 68 + f8 * 4] = P;
        }
    }
    __syncthreads();

    // ---- wave geometry ----
    int w = tid >> 6;
    int l = tid & 63;
    int mtile = w >> 1;
    int nhalf = w & 1;
    int lr = l & 15;
    int lq = l >> 4;

    // ---- phase B: H[32x256] = Ax @ W1 via MFMA; 32 mfma/wave ----
    f4acc acc1[8] = {};
#pragma unroll
    for (int ks = 0; ks < 4; ++ks) {
        bfrag a = as_bfrag(*(const uint4*)&AxP[(mtile * 16 + lr) * 68 + ks * 16 + lq * 4]);
#pragma unroll
        for (int nt = 0; nt < 8; ++nt) {
            bfrag b = as_bfrag(W1f[(ks * 16 + nhalf * 8 + nt) * 64 + l]);
            acc1[nt] = __builtin_amdgcn_mfma_f32_16x16x32_bf16(a, b, acc1[nt], 0, 0, 0);
        }
    }
    __syncthreads();  // all AxP reads done before HcS overwrite

    // ---- H epilogue: +b1, relu, bf16, to LDS ----
#pragma unroll
    for (int nt = 0; nt < 8; ++nt) {
        int col = nhalf * 128 + nt * 16 + lr;
        float bias = b1[col];
#pragma unroll
        for (int r = 0; r < 4; ++r) {
            int row = mtile * 16 + lq * 4 + r;
            float v = fmaxf(acc1[nt][r] + bias, 0.f);
            HcS[row * 264 + col] = (unsigned short)f2bf(v);
        }
    }
    __syncthreads();

    // ---- phase C: t2 = H @ W2 via MFMA; 16 mfma/wave ----
    f4acc acc2[2] = {};
#pragma unroll
    for (int ks = 0; ks < 8; ++ks) {
        bfrag a = as_bfrag(*(const uint4*)&HcS[(mtile * 16 + lr) * 264 + ks * 32 + lq * 8]);
#pragma unroll
        for (int nt = 0; nt < 2; ++nt) {
            bfrag b = as_bfrag(W2f[(ks * 4 + nhalf * 2 + nt) * 64 + l]);
            acc2[nt] = __builtin_amdgcn_mfma_f32_16x16x32_bf16(a, b, acc2[nt], 0, 0, 0);
        }
    }

    // ---- write t2b = bf16(dinv * acc2) ----
#pragma unroll
    for (int nt = 0; nt < 2; ++nt) {
        int col = nhalf * 32 + nt * 16 + lr;
#pragma unroll
        for (int r = 0; r < 4; ++r) {
            int row = bm0 + mtile * 16 + lq * 4 + r;
            if (row < N_NODES) {
                float d = dinv[row];
                t2b[(size_t)row * 64 + col] = (unsigned short)f2bf(d * acc2[nt][r]);
            }
        }
    }
}

// ---------------- layer 2 pull-gather: unmasked unroll-16 main + masked-8 tail ----
__global__ __launch_bounds__(256) void l2_gather_kernel(const unsigned* __restrict__ t2b,
                                                        const int* __restrict__ row_ptr,
                                                        const unsigned short* __restrict__ eidx,
                                                        const float* __restrict__ dinv,
                                                        const float* __restrict__ b2,
                                                        float* __restrict__ out) {
    int tid = threadIdx.x;
    int f8 = tid & 7;
    int nl = tid >> 3;
    int c = blockIdx.x * 32 + nl;
    if (c >= N_NODES) return;
    uint4 S = ((const uint4*)t2b)[(size_t)c * 8 + f8];
    float acc[8];
    acc[0] = bflo(S.x); acc[1] = bfhi(S.x);
    acc[2] = bflo(S.y); acc[3] = bfhi(S.y);
    acc[4] = bflo(S.z); acc[5] = bfhi(S.z);
    acc[6] = bflo(S.w); acc[7] = bfhi(S.w);
    int k = row_ptr[c];
    int k1 = row_ptr[c + 1];
    int kmain = k + ((k1 - k) & ~15);
    for (; k < kmain; k += 16) {
        int r[16];
#pragma unroll
        for (int j = 0; j < 16; ++j) r[j] = eidx[k + j];
        uint4 U[16];
#pragma unroll
        for (int j = 0; j < 16; ++j) U[j] = ((const uint4*)t2b)[(size_t)r[j] * 8 + f8];
#pragma unroll
        for (int j = 0; j < 16; ++j) {
            acc[0] += bflo(U[j].x); acc[1] += bfhi(U[j].x);
            acc[2] += bflo(U[j].y); acc[3] += bfhi(U[j].y);
            acc[4] += bflo(U[j].z); acc[5] += bfhi(U[j].z);
            acc[6] += bflo(U[j].w); acc[7] += bfhi(U[j].w);
        }
    }
    for (; k < k1; k += 8) {
        int r[8];
        float m[8];
#pragma unroll
        for (int j = 0; j < 8; ++j) {
            int idx = (k + j < k1) ? k + j : k1 - 1;
            r[j] = eidx[idx];
            m[j] = (k + j < k1) ? 1.f : 0.f;
        }
        uint4 U[8];
#pragma unroll
        for (int j = 0; j < 8; ++j) U[j] = ((const uint4*)t2b)[(size_t)r[j] * 8 + f8];
#pragma unroll
        for (int j = 0; j < 8; ++j) {
            acc[0] = fmaf(m[j], bflo(U[j].x), acc[0]);
            acc[1] = fmaf(m[j], bfhi(U[j].x), acc[1]);
            acc[2] = fmaf(m[j], bflo(U[j].y), acc[2]);
            acc[3] = fmaf(m[j], bfhi(U[j].y), acc[3]);
            acc[4] = fmaf(m[j], bflo(U[j].z), acc[4]);
            acc[5] = fmaf(m[j], bfhi(U[j].z), acc[5]);
            acc[6] = fmaf(m[j], bflo(U[j].w), acc[6]);
            acc[7] = fmaf(m[j], bfhi(U[j].w), acc[7]);
        }
    }
    float dc = dinv[c];
    float4 b2a = *(const float4*)&b2[f8 * 8];
    float4 b2b = *(const float4*)&b2[f8 * 8 + 4];
    float4 o0, o1;
    o0.x = fmaf(dc, acc[0], b2a.x);
    o0.y = fmaf(dc, acc[1], b2a.y);
    o0.z = fmaf(dc, acc[2], b2a.z);
    o0.w = fmaf(dc, acc[3], b2a.w);
    o1.x = fmaf(dc, acc[4], b2b.x);
    o1.y = fmaf(dc, acc[5], b2b.y);
    o1.z = fmaf(dc, acc[6], b2b.z);
    o1.w = fmaf(dc, acc[7], b2b.w);
    ((float4*)out)[(size_t)c * 16 + f8 * 2] = o0;
    ((float4*)out)[(size_t)c * 16 + f8 * 2 + 1] = o1;
}

// ---------------- launch ----------------

extern "C" void kernel_launch(void* const* d_in, const int* in_sizes, int n_in,
                              void* d_out, int out_size, void* d_ws, size_t ws_size,
                              hipStream_t stream) {
    const float* x = (const float*)d_in[0];
    const int* edge_index = (const int*)d_in[1];
    const float* W1 = (const float*)d_in[2];
    const float* b1 = (const float*)d_in[3];
    const float* W2 = (const float*)d_in[4];
    const float* b2 = (const float*)d_in[5];
    float* out = (float*)d_out;

    const int* rows = edge_index;            // source nodes
    const int* cols = edge_index + N_EDGES;  // target nodes

    char* ws = (char*)d_ws;
    int* row_ptr = (int*)(ws + OFF_ROWPTR);
    int* cnt = (int*)(ws + OFF_CNT);
    float* dinv = (float*)(ws + OFF_DINV);
    int* bsum = (int*)(ws + OFF_BSUM);
    unsigned short* eidx = (unsigned short*)(ws + OFF_EIDX);
    unsigned short* elocal = (unsigned short*)(ws + OFF_ELOC);
    unsigned* xb = (unsigned*)(ws + OFF_XB);
    unsigned* t2b = (unsigned*)(ws + OFF_T2B);
    unsigned* W1f = (unsigned*)(ws + OFF_W1F);
    unsigned* W2f = (unsigned*)(ws + OFF_W2F);

    const int BT = 256;

    wprep_zero_kernel<<<SCAN_NB, 256, 0, stream>>>(W1, W2, W1f, W2f, cnt);
    hist_elocal_kernel<<<(N_EDGES + BT - 1) / BT, BT, 0, stream>>>(cols, cnt, elocal, N_EDGES);
    bsum_kernel<<<SCAN_NB, 256, 0, stream>>>(cnt, bsum);
    bscan_kernel<<<1, 256, 0, stream>>>(bsum);
    rowptr_kernel<<<SCAN_NB, 256, 0, stream>>>(cnt, bsum, row_ptr, dinv);
    scatter_cvt_kernel<<<(N_EDGES + BT - 1) / BT, BT, 0, stream>>>(
        rows, cols, row_ptr, elocal, eidx, x, dinv, xb);

    fused12_kernel<<<(N_NODES + 31) / 32, 256, 0, stream>>>(
        xb, row_ptr, eidx, dinv, (const uint4*)W1f, b1, (const uint4*)W2f, (unsigned short*)t2b);
    l2_gather_kernel<<<(N_NODES + 31) / 32, 256, 0, stream>>>(t2b, row_ptr, eidx, dinv, b2, out);
}